// Round 2
// baseline (478.056 us; speedup 1.0000x reference)
//
#include <hip/hip_runtime.h>
#include <hip/hip_bf16.h>

#define K_TOP 10
#define PS 7
#define HD 4
#define QN 4096
#define TN 4
#define CN 64
#define HN 256
#define WN 256
#define K0 15
#define CH 16            // CN / HD
#define SP (PS * PS)     // 49
#define OUT_PER_Q (SP * CN)  // 3136
#define NTHREADS 448     // 64 c_all * 7 rows, one row-task per thread

__global__ __launch_bounds__(NTHREADS) void wpsum_kernel(
    const float* __restrict__ vid,
    const float* __restrict__ dists,
    const int*   __restrict__ inds,
    float*       __restrict__ out)
{
    __shared__ float s_w[HD][K_TOP];
    __shared__ int   s_base[HD][K_TOP];
    __shared__ float s_acc[CN][SP + 1];   // 64 x 50 f32 = 12.8 KB, padded

    const int q = blockIdx.x;
    const int t = threadIdx.x;

    // Stage weights and precomputed gather base offsets for all 4 heads x 10 k.
    if (t < HD * K_TOP) {
        const int h = t / K_TOP;
        const int k = t - h * K_TOP;
        const int idx = (h * QN + q) * K0 + k;
        s_w[h][k] = dists[idx];
        const int tt = inds[idx * 3 + 0];
        const int ii = inds[idx * 3 + 1];
        const int jj = inds[idx * 3 + 2];
        s_base[h][k] = ((tt * CN + h * CH) * HN + ii) * WN + jj;
    }
    __syncthreads();

    // One (channel, patch-row) per thread: 64 channels x 7 rows = 448 tasks.
    // Each task reads a 7-float contiguous row segment per k via two
    // overlapping 16B loads (alignment-safe memcpy), accumulating 7 outputs.
    const int c_all = t / 7;          // 0..63  (h*16 + c)
    const int pi    = t - c_all * 7;  // 0..6
    const int h = c_all >> 4;
    const int c = c_all & 15;
    const int coff = c * (HN * WN) + pi * WN;

    float acc[PS] = {0.f, 0.f, 0.f, 0.f, 0.f, 0.f, 0.f};
    #pragma unroll
    for (int k = 0; k < K_TOP; ++k) {
        const float w = s_w[h][k];
        const float* p = vid + s_base[h][k] + coff;
        float4 a, b;
        __builtin_memcpy(&a, p, 16);       // floats 0..3
        __builtin_memcpy(&b, p + 3, 16);   // floats 3..6 (overlap avoids OOB)
        acc[0] = fmaf(w, a.x, acc[0]);
        acc[1] = fmaf(w, a.y, acc[1]);
        acc[2] = fmaf(w, a.z, acc[2]);
        acc[3] = fmaf(w, a.w, acc[3]);
        acc[4] = fmaf(w, b.y, acc[4]);
        acc[5] = fmaf(w, b.z, acc[5]);
        acc[6] = fmaf(w, b.w, acc[6]);
    }

    #pragma unroll
    for (int j = 0; j < PS; ++j) {
        s_acc[c_all][pi * PS + j] = acc[j];
    }
    __syncthreads();

    // Coalesced store in output-native order: out[q*3136 + s*64 + c_all].
    float* outq = out + q * OUT_PER_Q;
    for (int e = t; e < OUT_PER_Q; e += NTHREADS) {
        const int s     = e >> 6;   // e = s*64 + c_all
        const int c_all2 = e & 63;
        outq[e] = s_acc[c_all2][s];
    }
}

extern "C" void kernel_launch(void* const* d_in, const int* in_sizes, int n_in,
                              void* d_out, int out_size, void* d_ws, size_t ws_size,
                              hipStream_t stream) {
    const float* vid   = (const float*)d_in[0];
    const float* dists = (const float*)d_in[1];
    const int*   inds  = (const int*)d_in[2];
    float* out = (float*)d_out;

    wpsum_kernel<<<QN, NTHREADS, 0, stream>>>(vid, dists, inds, out);
}

// Round 3
// 113.607 us; speedup vs baseline: 4.2080x; 4.2080x over previous
//
#include <hip/hip_runtime.h>
#include <hip/hip_bf16.h>

#define K_TOP 10
#define PS 7
#define HD 4
#define QN 4096
#define TN 4
#define CN 64
#define HN 256
#define WN 256
#define K0 15
#define CH 16            // CN / HD
#define SP (PS * PS)     // 49
#define OUT_PER_Q (SP * CN)  // 3136
#define VID_BYTES (TN * CN * HN * WN * 4)  // 64 MB

// ---- Pass 1: vid [T,C,H,W] -> vidT [HD,T,H,W,16]  (head-channel innermost) ----
// grid = TN*HN*HD blocks (t,i,h), 256 threads. Coalesced read + coalesced write.
__global__ __launch_bounds__(256) void transpose_kernel(
    const float* __restrict__ vid, float* __restrict__ vidT)
{
    __shared__ float s[CH][260];   // stride 260 -> bank = (c*4+j)%32, 2-way max (free)
    const int b = blockIdx.x;
    const int h = b & 3;
    const int i = (b >> 2) & 255;
    const int t = b >> 10;
    const int tid = threadIdx.x;

    for (int e = tid; e < CH * WN; e += 256) {
        const int cc = e >> 8;       // 0..15
        const int j  = e & 255;
        s[cc][j] = vid[(((t * CN) + (h * CH + cc)) * HN + i) * WN + j];
    }
    __syncthreads();
    float* dst = vidT + (size_t)(((h * TN + t) * HN + i) * WN) * CH;
    for (int e = tid; e < CH * WN; e += 256) {
        dst[e] = s[e & 15][e >> 4];  // contiguous global write
    }
}

// ---- Pass 2: gather-weighted sum from vidT ----
// One block per q. Thread (g,r): g=position (pi,pj) 0..48, r=float4 chunk of 16ch.
__global__ __launch_bounds__(256) void wpsum_gather(
    const float* __restrict__ vidT,
    const float* __restrict__ dists,
    const int*   __restrict__ inds,
    float*       __restrict__ out)
{
    __shared__ float s_w[HD][K_TOP];
    __shared__ int   s_base[HD][K_TOP];

    const int q = blockIdx.x;
    const int tid = threadIdx.x;

    if (tid < HD * K_TOP) {
        const int h = tid / K_TOP;
        const int k = tid - h * K_TOP;
        const int idx = (h * QN + q) * K0 + k;
        s_w[h][k] = dists[idx];
        const int tt = inds[idx * 3 + 0];
        const int ii = inds[idx * 3 + 1];
        const int jj = inds[idx * 3 + 2];
        s_base[h][k] = (((h * TN + tt) * HN + ii) * WN + jj) * CH;
    }
    __syncthreads();

    const int g = tid >> 2;   // position 0..63 (49 active)
    const int r = tid & 3;    // float4 within 16 channels
    if (g >= SP) return;
    const int pi = g / PS;
    const int pj = g - pi * PS;
    const int poff = (pi * WN + pj) * CH + r * 4;

    float* outq = out + (size_t)q * OUT_PER_Q + g * CN;

    #pragma unroll
    for (int h = 0; h < HD; ++h) {
        float4 acc = {0.f, 0.f, 0.f, 0.f};
        #pragma unroll
        for (int k = 0; k < K_TOP; ++k) {
            const float w = s_w[h][k];
            const float4 v = *(const float4*)(vidT + s_base[h][k] + poff);
            acc.x = fmaf(w, v.x, acc.x);
            acc.y = fmaf(w, v.y, acc.y);
            acc.z = fmaf(w, v.z, acc.z);
            acc.w = fmaf(w, v.w, acc.w);
        }
        *(float4*)(outq + h * CH + r * 4) = acc;
    }
}

// ---- Fallback (round-1 kernel) if ws_size < 64 MB ----
__global__ __launch_bounds__(256) void wpsum_fallback(
    const float* __restrict__ vid,
    const float* __restrict__ dists,
    const int*   __restrict__ inds,
    float*       __restrict__ out)
{
    __shared__ float s_w[HD][K_TOP];
    __shared__ int   s_base[HD][K_TOP];
    __shared__ float s_acc[CN][SP + 1];

    const int q = blockIdx.x;
    const int t = threadIdx.x;

    if (t < HD * K_TOP) {
        const int h = t / K_TOP;
        const int k = t - h * K_TOP;
        const int idx = (h * QN + q) * K0 + k;
        s_w[h][k] = dists[idx];
        const int tt = inds[idx * 3 + 0];
        const int ii = inds[idx * 3 + 1];
        const int jj = inds[idx * 3 + 2];
        s_base[h][k] = ((tt * CN + h * CH) * HN + ii) * WN + jj;
    }
    __syncthreads();

    for (int e = t; e < OUT_PER_Q; e += 256) {
        const int c_all = e / SP;
        const int s     = e - c_all * SP;
        const int h  = c_all >> 4;
        const int c  = c_all & 15;
        const int pi = s / PS;
        const int pj = s - pi * PS;
        const int off = c * (HN * WN) + pi * WN + pj;
        float acc = 0.f;
        #pragma unroll
        for (int k = 0; k < K_TOP; ++k)
            acc = fmaf(s_w[h][k], vid[s_base[h][k] + off], acc);
        s_acc[c_all][s] = acc;
    }
    __syncthreads();

    float* outq = out + q * OUT_PER_Q;
    for (int e = t; e < OUT_PER_Q; e += 256) {
        outq[e] = s_acc[e & 63][e >> 6];
    }
}

extern "C" void kernel_launch(void* const* d_in, const int* in_sizes, int n_in,
                              void* d_out, int out_size, void* d_ws, size_t ws_size,
                              hipStream_t stream) {
    const float* vid   = (const float*)d_in[0];
    const float* dists = (const float*)d_in[1];
    const int*   inds  = (const int*)d_in[2];
    float* out = (float*)d_out;

    if (ws_size >= (size_t)VID_BYTES) {
        float* vidT = (float*)d_ws;
        transpose_kernel<<<TN * HN * HD, 256, 0, stream>>>(vid, vidT);
        wpsum_gather<<<QN, 256, 0, stream>>>(vidT, dists, inds, out);
    } else {
        wpsum_fallback<<<QN, 256, 0, stream>>>(vid, dists, inds, out);
    }
}

// Round 4
// 73.944 us; speedup vs baseline: 6.4651x; 1.5364x over previous
//
#include <hip/hip_runtime.h>
#include <hip/hip_fp16.h>

#define K_TOP 10
#define PS 7
#define HD 4
#define QN 4096
#define TN 4
#define CN 64
#define HN 256
#define WN 256
#define K0 15
#define CH 16            // CN / HD
#define SP (PS * PS)     // 49
#define OUT_PER_Q (SP * CN)  // 3136
#define VIDT_BYTES (TN * CN * HN * WN * 2)  // 32 MB (f16)

// ---- Pass 1: vid [T,C,H,W] f32 -> vidT [HD,T,H,W,16] f16 ----
__global__ __launch_bounds__(256) void transpose_f16_kernel(
    const float* __restrict__ vid, __half* __restrict__ vidT)
{
    __shared__ float s[CH][WN + 4];   // stride 260 floats -> <=2-way banks (free)
    const int b = blockIdx.x;
    const int h = b & 3;
    const int i = (b >> 2) & 255;
    const int t = b >> 10;
    const int tid = threadIdx.x;

    for (int e = tid; e < CH * WN; e += 256) {
        const int cc = e >> 8;       // 0..15
        const int j  = e & 255;
        s[cc][j] = vid[(((t * CN) + (h * CH + cc)) * HN + i) * WN + j];
    }
    __syncthreads();

    // dst row: position j innermost-major over 16 half channels, contiguous.
    uint2* dst = (uint2*)(vidT + (size_t)(((h * TN + t) * HN + i) * WN) * CH);
    for (int e = tid; e < CH * WN / 4; e += 256) {   // one uint2 = 4 half ch
        const int c4 = e & 3;        // channel quad
        const int j  = e >> 2;       // position
        const __half2 lo = __floats2half2_rn(s[4 * c4 + 0][j], s[4 * c4 + 1][j]);
        const __half2 hi = __floats2half2_rn(s[4 * c4 + 2][j], s[4 * c4 + 3][j]);
        uint2 pk;
        __builtin_memcpy(&pk.x, &lo, 4);
        __builtin_memcpy(&pk.y, &hi, 4);
        dst[e] = pk;
    }
}

// ---- Pass 2: gather-weighted sum from f16 vidT, f32 accumulate ----
// 256 threads handle 2 q's. Per q: thread (g,r), g=position 0..48, r=8ch chunk.
__global__ __launch_bounds__(256) void wpsum_gather_f16(
    const __half* __restrict__ vidT,
    const float* __restrict__ dists,
    const int*   __restrict__ inds,
    float*       __restrict__ out)
{
    __shared__ float s_w[2][HD][K_TOP];
    __shared__ int   s_base[2][HD][K_TOP];

    const int q0 = blockIdx.x * 2;
    const int tid = threadIdx.x;

    if (tid < 2 * HD * K_TOP) {
        const int sub  = tid / (HD * K_TOP);
        const int rest = tid - sub * (HD * K_TOP);
        const int h = rest / K_TOP;
        const int k = rest - h * K_TOP;
        const int idx = (h * QN + (q0 + sub)) * K0 + k;
        s_w[sub][h][k] = dists[idx];
        const int tt = inds[idx * 3 + 0];
        const int ii = inds[idx * 3 + 1];
        const int jj = inds[idx * 3 + 2];
        s_base[sub][h][k] = (((h * TN + tt) * HN + ii) * WN + jj) * CH;
    }
    __syncthreads();

    const int sub = tid >> 7;
    const int t2  = tid & 127;
    const int g   = t2 >> 1;     // position 0..63 (49 active)
    const int r   = t2 & 1;      // 8-channel chunk
    if (g >= SP) return;
    const int pi = g / PS;
    const int pj = g - pi * PS;
    const int poff = (pi * WN + pj) * CH + r * 8;

    float acc[HD][8];
    #pragma unroll
    for (int h = 0; h < HD; ++h)
        #pragma unroll
        for (int j = 0; j < 8; ++j) acc[h][j] = 0.f;

    #pragma unroll
    for (int h = 0; h < HD; ++h) {
        #pragma unroll
        for (int k = 0; k < K_TOP; ++k) {
            const float w = s_w[sub][h][k];
            const uint4 u = *(const uint4*)(vidT + s_base[sub][h][k] + poff);
            __half2 h0, h1, h2, h3;
            __builtin_memcpy(&h0, &u.x, 4);
            __builtin_memcpy(&h1, &u.y, 4);
            __builtin_memcpy(&h2, &u.z, 4);
            __builtin_memcpy(&h3, &u.w, 4);
            const float2 f0 = __half22float2(h0);
            const float2 f1 = __half22float2(h1);
            const float2 f2 = __half22float2(h2);
            const float2 f3 = __half22float2(h3);
            acc[h][0] = fmaf(w, f0.x, acc[h][0]);
            acc[h][1] = fmaf(w, f0.y, acc[h][1]);
            acc[h][2] = fmaf(w, f1.x, acc[h][2]);
            acc[h][3] = fmaf(w, f1.y, acc[h][3]);
            acc[h][4] = fmaf(w, f2.x, acc[h][4]);
            acc[h][5] = fmaf(w, f2.y, acc[h][5]);
            acc[h][6] = fmaf(w, f3.x, acc[h][6]);
            acc[h][7] = fmaf(w, f3.y, acc[h][7]);
        }
    }

    float* outq = out + (size_t)(q0 + sub) * OUT_PER_Q + g * CN;
    #pragma unroll
    for (int h = 0; h < HD; ++h) {
        float4 v0 = {acc[h][0], acc[h][1], acc[h][2], acc[h][3]};
        float4 v1 = {acc[h][4], acc[h][5], acc[h][6], acc[h][7]};
        *(float4*)(outq + h * CH + r * 8)     = v0;
        *(float4*)(outq + h * CH + r * 8 + 4) = v1;
    }
}

// ---- Fallback (round-1 kernel) if workspace too small ----
__global__ __launch_bounds__(256) void wpsum_fallback(
    const float* __restrict__ vid,
    const float* __restrict__ dists,
    const int*   __restrict__ inds,
    float*       __restrict__ out)
{
    __shared__ float s_w[HD][K_TOP];
    __shared__ int   s_base[HD][K_TOP];
    __shared__ float s_acc[CN][SP + 1];

    const int q = blockIdx.x;
    const int t = threadIdx.x;

    if (t < HD * K_TOP) {
        const int h = t / K_TOP;
        const int k = t - h * K_TOP;
        const int idx = (h * QN + q) * K0 + k;
        s_w[h][k] = dists[idx];
        const int tt = inds[idx * 3 + 0];
        const int ii = inds[idx * 3 + 1];
        const int jj = inds[idx * 3 + 2];
        s_base[h][k] = ((tt * CN + h * CH) * HN + ii) * WN + jj;
    }
    __syncthreads();

    for (int e = t; e < OUT_PER_Q; e += 256) {
        const int c_all = e / SP;
        const int s     = e - c_all * SP;
        const int h  = c_all >> 4;
        const int c  = c_all & 15;
        const int pi = s / PS;
        const int pj = s - pi * PS;
        const int off = c * (HN * WN) + pi * WN + pj;
        float acc = 0.f;
        #pragma unroll
        for (int k = 0; k < K_TOP; ++k)
            acc = fmaf(s_w[h][k], vid[s_base[h][k] + off], acc);
        s_acc[c_all][s] = acc;
    }
    __syncthreads();

    float* outq = out + q * OUT_PER_Q;
    for (int e = t; e < OUT_PER_Q; e += 256) {
        outq[e] = s_acc[e & 63][e >> 6];
    }
}

extern "C" void kernel_launch(void* const* d_in, const int* in_sizes, int n_in,
                              void* d_out, int out_size, void* d_ws, size_t ws_size,
                              hipStream_t stream) {
    const float* vid   = (const float*)d_in[0];
    const float* dists = (const float*)d_in[1];
    const int*   inds  = (const int*)d_in[2];
    float* out = (float*)d_out;

    if (ws_size >= (size_t)VIDT_BYTES) {
        __half* vidT = (__half*)d_ws;
        transpose_f16_kernel<<<TN * HN * HD, 256, 0, stream>>>(vid, vidT);
        wpsum_gather_f16<<<QN / 2, 256, 0, stream>>>(vidT, dists, inds, out);
    } else {
        wpsum_fallback<<<QN, 256, 0, stream>>>(vid, dists, inds, out);
    }
}